// Round 12
// baseline (285.643 us; speedup 1.0000x reference)
//
#include <hip/hip_runtime.h>

#define B_ 16
#define N_ 1024
#define K_ 16
#define F_ 128
#define L_ 4
#define DIN_ 257

typedef __bf16 bf16x8 __attribute__((ext_vector_type(8)));
typedef float f32x4 __attribute__((ext_vector_type(4)));

__device__ __forceinline__ float silu_f(float x) {
    return x / (1.0f + __expf(-x));
}

__device__ __forceinline__ unsigned short f2bf_bits(float f) {
    unsigned u = __builtin_bit_cast(unsigned, f);
    return (unsigned short)((u + 0x7FFFu + ((u >> 16) & 1u)) >> 16);
}

// ---------------- prep: weight pack/convert + embed (fused; r11 verbatim) ----------------
__global__ __launch_bounds__(256) void k_prep(const int* __restrict__ z,
                                              const float* __restrict__ emb,
                                              const float* __restrict__ W1,
                                              const float* __restrict__ W2,
                                              const float* __restrict__ A1,
                                              float* __restrict__ h,
                                              unsigned short* __restrict__ hbf,
                                              unsigned short* __restrict__ Wt1,
                                              unsigned short* __restrict__ Wt2,
                                              unsigned short* __restrict__ At1) {
    int gid = blockIdx.x * 256 + threadIdx.x;
    int id = gid;
    if (id < L_ * 256 * 128) {
        int k = id & 127, n = (id >> 7) & 255, l = id >> 15;
        float v = (n < 128) ? W1[(size_t)l * DIN_ * F_ + (size_t)k * F_ + n]
                            : W1[(size_t)l * DIN_ * F_ + (size_t)(128 + k) * F_ + (n - 128)];
        Wt1[id] = f2bf_bits(v);
    } else {
        int id2 = id - L_ * 256 * 128;
        if (id2 < L_ * 128 * 128) {
            int k = id2 & 127, n = (id2 >> 7) & 127, l = id2 >> 14;
            Wt2[id2] = f2bf_bits(W2[(size_t)l * F_ * F_ + (size_t)k * F_ + n]);
        } else {
            int id3 = id2 - L_ * 128 * 128;
            if (id3 < 256 * 128) {
                int k = id3 & 127, n = id3 >> 7;
                float v = (n < 128) ? A1[(size_t)k * 128 + n]
                                    : A1[(size_t)(128 + k) * 128 + (n - 128)];
                At1[id3] = f2bf_bits(v);
            }
        }
    }
    {
        int t = gid;
        int node = t >> 5;
        int f4 = (t & 31) << 2;
        int zi = z[node];
        float4 v = *reinterpret_cast<const float4*>(&emb[zi * F_ + f4]);
        *reinterpret_cast<float4*>(&h[node * F_ + f4]) = v;
        ushort4 pk;
        pk.x = f2bf_bits(v.x); pk.y = f2bf_bits(v.y);
        pk.z = f2bf_bits(v.z); pk.w = f2bf_bits(v.w);
        *reinterpret_cast<ushort4*>(&hbf[node * F_ + f4]) = pk;
    }
}

// ---------------- front: G1-layer0 GEMM (blocks 0..1023) || KNN (1024..5119) ----------------
// r11 verbatim (validated, 119 us, VGPR 64).
__global__ __launch_bounds__(256) void k_front(const float* __restrict__ x,
                                               const float* __restrict__ cell,
                                               int* __restrict__ idx_o,
                                               float* __restrict__ vec_o,
                                               float* __restrict__ d_o,
                                               const unsigned short* __restrict__ hbf,
                                               const unsigned short* __restrict__ Wt1,
                                               float* __restrict__ uv0) {
    __shared__ float fr[N_ * 3];
    int gb = blockIdx.x;
    int wave = threadIdx.x >> 6;
    int lane = threadIdx.x & 63;

    if (gb < 1024) {
        int tile = gb * 4 + wave;
        int mt = tile >> 3, nt = tile & 7;
        int fr16 = lane & 15, ko = lane >> 4;
        const unsigned short* Ap = hbf + (size_t)(mt * 32 + fr16) * 128 + ko * 8;
        const unsigned short* Bp = Wt1 + (size_t)(nt * 32 + fr16) * 128 + ko * 8;
        f32x4 acc00 = {0.f, 0.f, 0.f, 0.f}, acc01 = acc00, acc10 = acc00, acc11 = acc00;
#pragma unroll
        for (int ks = 0; ks < 4; ++ks) {
            bf16x8 a0 = *reinterpret_cast<const bf16x8*>(Ap + ks * 32);
            bf16x8 a1 = *reinterpret_cast<const bf16x8*>(Ap + 16 * 128 + ks * 32);
            bf16x8 b0 = *reinterpret_cast<const bf16x8*>(Bp + ks * 32);
            bf16x8 b1 = *reinterpret_cast<const bf16x8*>(Bp + 16 * 128 + ks * 32);
            acc00 = __builtin_amdgcn_mfma_f32_16x16x32_bf16(a0, b0, acc00, 0, 0, 0);
            acc01 = __builtin_amdgcn_mfma_f32_16x16x32_bf16(a0, b1, acc01, 0, 0, 0);
            acc10 = __builtin_amdgcn_mfma_f32_16x16x32_bf16(a1, b0, acc10, 0, 0, 0);
            acc11 = __builtin_amdgcn_mfma_f32_16x16x32_bf16(a1, b1, acc11, 0, 0, 0);
        }
        int mrow = mt * 32 + ko * 4;
        int cbase = nt * 32 + fr16;
#define EPI_(FM, FN, ACC)                                                    \
    {                                                                        \
        int cc = cbase + FN * 16;                                            \
        _Pragma("unroll") for (int r = 0; r < 4; ++r) {                      \
            int row = mrow + FM * 16 + r;                                    \
            uv0[(size_t)row * 256 + cc] = ACC[r];                            \
        }                                                                    \
    }
        EPI_(0, 0, acc00) EPI_(0, 1, acc01) EPI_(1, 0, acc10) EPI_(1, 1, acc11)
#undef EPI_
        return;
    }

    int kb = gb - 1024;
    int b = kb >> 8;
    int ib = (kb & 255) << 2;
    const float* xb = x + b * N_ * 3;
    for (int u = threadIdx.x; u < N_ * 3; u += 256) {
        float xv = xb[u];
        fr[u] = xv - floorf(xv);
    }
    __syncthreads();
    int i = ib + wave;

    const float* cb = cell + b * 9;
    float c00 = cb[0], c01 = cb[1], c02 = cb[2];
    float c10 = cb[3], c11 = cb[4], c12 = cb[5];
    float c20 = cb[6], c21 = cb[7], c22 = cb[8];
    float fi0 = fr[i * 3 + 0], fi1 = fr[i * 3 + 1], fi2 = fr[i * 3 + 2];

    unsigned long long k[16];
#pragma unroll
    for (int t = 0; t < 16; ++t) {
        int j = t * 64 + lane;
        float r0 = fr[j * 3 + 0] - fi0;
        float r1 = fr[j * 3 + 1] - fi1;
        float r2 = fr[j * 3 + 2] - fi2;
        float s0f = (r0 > 0.f) ? -1.f : 0.f;
        float s1f = (r1 > 0.f) ? -1.f : 0.f;
        float s2f = (r2 > 0.f) ? -1.f : 0.f;
        int sid_base = ((r0 > 0.f) ? 0 : 9) + ((r1 > 0.f) ? 0 : 3) + ((r2 > 0.f) ? 0 : 1);
        float rx0 = r0 + s0f, rx1 = r0 + (s0f + 1.0f);
        float ry0 = r1 + s1f, ry1 = r1 + (s1f + 1.0f);
        float rz0 = r2 + s2f, rz1 = r2 + (s2f + 1.0f);
        float best = 3e38f;
        int bsid = 0;
#pragma unroll
        for (int cbo = 0; cbo < 8; ++cbo) {  // bit2=i0, bit1=i1, bit0=i2 (ascending sid)
            float rs0 = (cbo & 4) ? rx1 : rx0;
            float rs1 = (cbo & 2) ? ry1 : ry0;
            float rs2 = (cbo & 1) ? rz1 : rz0;
            float cx = fmaf(rs2, c20, fmaf(rs1, c10, rs0 * c00));
            float cy = fmaf(rs2, c21, fmaf(rs1, c11, rs0 * c01));
            float cz = fmaf(rs2, c22, fmaf(rs1, c12, rs0 * c02));
            float d2 = fmaf(cz, cz, fmaf(cy, cy, cx * cx));
            int sid = sid_base + ((cbo >> 2) & 1) * 9 + ((cbo >> 1) & 1) * 3 + (cbo & 1);
            if (d2 < best) { best = d2; bsid = sid; }
        }
        if (j == i) best = 3e38f;
        unsigned db = __builtin_bit_cast(unsigned, best);
        k[t] = ((unsigned long long)db << 32) | (unsigned)((j << 5) | bsid);
    }

#define CE_(a, b)                                              \
    {                                                          \
        unsigned long long x_ = k[a], y_ = k[b];               \
        bool s_ = y_ < x_;                                     \
        k[a] = s_ ? y_ : x_;                                   \
        k[b] = s_ ? x_ : y_;                                   \
    }
    CE_(0,1) CE_(2,3) CE_(4,5) CE_(6,7) CE_(8,9) CE_(10,11) CE_(12,13) CE_(14,15)
    CE_(0,2) CE_(1,3) CE_(4,6) CE_(5,7) CE_(8,10) CE_(9,11) CE_(12,14) CE_(13,15)
    CE_(1,2) CE_(5,6) CE_(9,10) CE_(13,14)
    CE_(0,4) CE_(1,5) CE_(2,6) CE_(3,7) CE_(8,12) CE_(9,13) CE_(10,14) CE_(11,15)
    CE_(2,4) CE_(3,5) CE_(10,12) CE_(11,13)
    CE_(1,2) CE_(3,4) CE_(5,6) CE_(9,10) CE_(11,12) CE_(13,14)
    CE_(0,8) CE_(1,9) CE_(2,10) CE_(3,11) CE_(4,12) CE_(5,13) CE_(6,14) CE_(7,15)
    CE_(4,8) CE_(5,9) CE_(6,10) CE_(7,11)
    CE_(2,4) CE_(3,5) CE_(6,8) CE_(7,9) CE_(10,12) CE_(11,13)
    CE_(1,2) CE_(3,4) CE_(5,6) CE_(7,8) CE_(9,10) CE_(11,12) CE_(13,14)
#undef CE_

    unsigned long long sel = 0;
    for (int r = 0; r < 16; ++r) {
        unsigned long long m = k[0];
#pragma unroll
        for (int off = 32; off >= 1; off >>= 1) {
            unsigned long long o = __shfl_xor(m, off);
            if (o < m) m = o;
        }
        if (k[0] == m) {
#pragma unroll
            for (int t = 0; t < 15; ++t) k[t] = k[t + 1];
            k[15] = ~0ull;
        }
        if (lane == r) sel = m;
    }

    if (lane < 16) {
        unsigned pk = (unsigned)sel;
        int j = pk >> 5, sid = pk & 31;
        int s0 = sid / 9 - 1, s1 = (sid / 3) % 3 - 1, s2 = sid % 3 - 1;
        float rs0 = (fr[j * 3 + 0] - fi0) + (float)s0;
        float rs1 = (fr[j * 3 + 1] - fi1) + (float)s1;
        float rs2 = (fr[j * 3 + 2] - fi2) + (float)s2;
        float vx = fmaf(rs2, c20, fmaf(rs1, c10, rs0 * c00));
        float vy = fmaf(rs2, c21, fmaf(rs1, c11, rs0 * c01));
        float vz = fmaf(rs2, c22, fmaf(rs1, c12, rs0 * c02));
        float d2 = fmaf(vz, vz, fmaf(vy, vy, vx * vx));
        float dd = sqrtf(fmaxf(d2, 1e-12f));
        int node = b * N_ + i;
        int eo = node * K_ + lane;
        idx_o[eo] = j;
        d_o[eo] = dd;
        vec_o[eo * 3 + 0] = vx;
        vec_o[eo * 3 + 1] = vy;
        vec_o[eo * 3 + 2] = vz;
    }
}

// ---------------- fused layer, 8 nodes/block x 2048 blocks ----------------
// Edge loop split across two thread-halves (e0-7 || e8-15), combined in LDS.
// MFMA tiles zero-pad rows 8-15; writes guarded to rows 0-7.
__global__ __launch_bounds__(256) void k_layer8(const float* __restrict__ UVin,
                                                const int* __restrict__ idx,
                                                const float* __restrict__ nd,
                                                const float* __restrict__ w1d,
                                                const float* __restrict__ b1l,
                                                const unsigned short* __restrict__ W2t,
                                                const float* __restrict__ b2l,
                                                float* __restrict__ h,
                                                const unsigned short* __restrict__ W1n,
                                                float* __restrict__ UVout) {
    __shared__ __align__(16) unsigned short svl[16][136];
    __shared__ __align__(16) unsigned short hbl[16][136];
    __shared__ float partial[8][132];
    int tid = threadIdx.x;
    int gb = blockIdx.x;
    // XCD-friendly remap: blocks of one batch share gb%8.
    int batch = (gb & 7) + 8 * (gb >> 10);
    int ib = (gb >> 3) & 127;
    int node0 = batch * N_ + ib * 8;
    int bbase = batch * N_;
    int wave = tid >> 6, lane = tid & 63;
    int fr16 = lane & 15, ko = lane >> 4;

    // zero-pad rows 8..15 of svl/hbl (contiguous 2176 B each = 136 int4)
    for (int u = tid; u < 272; u += 256) {
        if (u < 136)
            reinterpret_cast<int4*>(&svl[8][0])[u] = make_int4(0, 0, 0, 0);
        else
            reinterpret_cast<int4*>(&hbl[8][0])[u - 136] = make_int4(0, 0, 0, 0);
    }

    // ---- edge: savg = mean_e silu(u_i + v_j + d*w1d + b1); e-halves split ----
    {
        int eh = tid >> 7;            // edge half: 0 -> e0..7, 1 -> e8..15
        int tq = tid & 127;
        int gn = tq >> 4, fc = tq & 15, f0 = fc << 3;
        int node = node0 + gn;
        int4 ji[2];
        float4 di[2];
#pragma unroll
        for (int q = 0; q < 2; ++q) {
            ji[q] = *reinterpret_cast<const int4*>(&idx[node * K_ + eh * 8 + q * 4]);
            di[q] = *reinterpret_cast<const float4*>(&nd[node * K_ + eh * 8 + q * 4]);
        }
        float u[8], wd[8], bb[8], acc[8];
#pragma unroll
        for (int q = 0; q < 8; q += 4) {
            float4 t = *reinterpret_cast<const float4*>(&UVin[(size_t)node * 256 + f0 + q]);
            u[q] = t.x; u[q + 1] = t.y; u[q + 2] = t.z; u[q + 3] = t.w;
            float4 t2 = *reinterpret_cast<const float4*>(&w1d[f0 + q]);
            wd[q] = t2.x; wd[q + 1] = t2.y; wd[q + 2] = t2.z; wd[q + 3] = t2.w;
            float4 t3 = *reinterpret_cast<const float4*>(&b1l[f0 + q]);
            bb[q] = t3.x; bb[q + 1] = t3.y; bb[q + 2] = t3.z; bb[q + 3] = t3.w;
        }
#pragma unroll
        for (int q = 0; q < 8; ++q) acc[q] = 0.f;
#pragma unroll
        for (int eq = 0; eq < 2; ++eq) {
            int j4[4] = {ji[eq].x, ji[eq].y, ji[eq].z, ji[eq].w};
            float d4[4] = {di[eq].x, di[eq].y, di[eq].z, di[eq].w};
            float4 va[4], vb[4];
#pragma unroll
            for (int e = 0; e < 4; ++e) {
                const float* vp = &UVin[(size_t)(bbase + j4[e]) * 256 + 128 + f0];
                va[e] = *reinterpret_cast<const float4*>(&vp[0]);
                vb[e] = *reinterpret_cast<const float4*>(&vp[4]);
            }
#pragma unroll
            for (int e = 0; e < 4; ++e) {
                float dd = d4[e];
                float v8[8] = {va[e].x, va[e].y, va[e].z, va[e].w,
                               vb[e].x, vb[e].y, vb[e].z, vb[e].w};
#pragma unroll
                for (int w = 0; w < 8; ++w) {
                    float pre = u[w] + v8[w] + fmaf(dd, wd[w], bb[w]);
                    acc[w] += silu_f(pre);
                }
            }
        }
        if (eh == 1) {
#pragma unroll
            for (int q = 0; q < 8; ++q) partial[gn][f0 + q] = acc[q];
        }
        __syncthreads();
        if (eh == 0) {
            const float inv_k = 1.0f / (float)K_;
            unsigned ow[4];
#pragma unroll
            for (int q = 0; q < 8; ++q) acc[q] += partial[gn][f0 + q];
#pragma unroll
            for (int q = 0; q < 4; ++q)
                ow[q] = (unsigned)f2bf_bits(acc[2 * q] * inv_k) |
                        ((unsigned)f2bf_bits(acc[2 * q + 1] * inv_k) << 16);
            *reinterpret_cast<int4*>(&svl[gn][f0]) = make_int4(ow[0], ow[1], ow[2], ow[3]);
        }
    }
    __syncthreads();

    // ---- GEMM2 (M=8 valid): h' = savg @ W2 + b2 + h ----
    {
        const unsigned short* Bp = W2t + (size_t)(wave * 32 + fr16) * 128 + ko * 8;
        bf16x8 a0[4], b0[4], b1f[4];
#pragma unroll
        for (int ks = 0; ks < 4; ++ks) {
            a0[ks] = *reinterpret_cast<const bf16x8*>(&svl[fr16][ks * 32 + ko * 8]);
            b0[ks] = *reinterpret_cast<const bf16x8*>(Bp + ks * 32);
            b1f[ks] = *reinterpret_cast<const bf16x8*>(Bp + 16 * 128 + ks * 32);
        }
        f32x4 acc00 = {0.f, 0.f, 0.f, 0.f}, acc01 = acc00;
#pragma unroll
        for (int ks = 0; ks < 4; ++ks) {
            acc00 = __builtin_amdgcn_mfma_f32_16x16x32_bf16(a0[ks], b0[ks], acc00, 0, 0, 0);
            acc01 = __builtin_amdgcn_mfma_f32_16x16x32_bf16(a0[ks], b1f[ks], acc01, 0, 0, 0);
        }
        int cb0 = wave * 32 + fr16;
        if (ko < 2) {
#define EPI2_(FN, ACC)                                                         \
    {                                                                          \
        int col = cb0 + FN * 16;                                               \
        float bv = b2l[col];                                                   \
        _Pragma("unroll") for (int r = 0; r < 4; ++r) {                        \
            int row = ko * 4 + r;                                              \
            int grow = node0 + row;                                            \
            float val = ACC[r] + bv + h[(size_t)grow * 128 + col];             \
            h[(size_t)grow * 128 + col] = val;                                 \
            hbl[row][col] = f2bf_bits(val);                                    \
        }                                                                      \
    }
            EPI2_(0, acc00) EPI2_(1, acc01)
#undef EPI2_
        }
    }
    __syncthreads();

    // ---- GEMM1-next (M=8 valid): uv_next = h' @ W1n ----
#pragma unroll
    for (int half = 0; half < 2; ++half) {
        int nt2 = wave + half * 4;
        const unsigned short* Bp = W1n + (size_t)(nt2 * 32 + fr16) * 128 + ko * 8;
        bf16x8 a0[4], b0[4], b1f[4];
#pragma unroll
        for (int ks = 0; ks < 4; ++ks) {
            a0[ks] = *reinterpret_cast<const bf16x8*>(&hbl[fr16][ks * 32 + ko * 8]);
            b0[ks] = *reinterpret_cast<const bf16x8*>(Bp + ks * 32);
            b1f[ks] = *reinterpret_cast<const bf16x8*>(Bp + 16 * 128 + ks * 32);
        }
        f32x4 acc00 = {0.f, 0.f, 0.f, 0.f}, acc01 = acc00;
#pragma unroll
        for (int ks = 0; ks < 4; ++ks) {
            acc00 = __builtin_amdgcn_mfma_f32_16x16x32_bf16(a0[ks], b0[ks], acc00, 0, 0, 0);
            acc01 = __builtin_amdgcn_mfma_f32_16x16x32_bf16(a0[ks], b1f[ks], acc01, 0, 0, 0);
        }
        int cb0 = nt2 * 32 + fr16;
        if (ko < 2) {
#define EPI1_(FN, ACC)                                                         \
    {                                                                          \
        int col = cb0 + FN * 16;                                               \
        _Pragma("unroll") for (int r = 0; r < 4; ++r) {                        \
            int row = ko * 4 + r;                                              \
            UVout[(size_t)(node0 + row) * 256 + col] = ACC[r];                 \
        }                                                                      \
    }
            EPI1_(0, acc00) EPI1_(1, acc01)
#undef EPI1_
        }
    }
}

// ---------------- final head (r11 verbatim) ----------------
__global__ __launch_bounds__(256) void k_final(const float* __restrict__ P,
                                               const int* __restrict__ idx,
                                               const float* __restrict__ nd,
                                               const float* __restrict__ nvec,
                                               const float* __restrict__ A1d,
                                               const float* __restrict__ a1v,
                                               const float* __restrict__ A2v,
                                               const float* __restrict__ a2v,
                                               const float* __restrict__ x,
                                               const float* __restrict__ cell,
                                               float* __restrict__ out) {
    __shared__ float plds[16][256];
    __shared__ float wlds[16][17];
    __shared__ float dclds[16][3];
    int gb = blockIdx.x;
    int batch = (gb & 7) + 8 * (gb >> 9);
    int ib = (gb >> 3) & 63;
    int node0 = batch * N_ + ib * 16;
    int bbase = batch * N_;
    int g = threadIdx.x >> 4, fc = threadIdx.x & 15;
    int node = node0 + g;
    int f0 = fc * 8;
    int4 ji[4];
    float4 di[4];
#pragma unroll
    for (int q = 0; q < 4; ++q) {
        ji[q] = *reinterpret_cast<const int4*>(&idx[node * K_ + q * 4]);
        di[q] = *reinterpret_cast<const float4*>(&nd[node * K_ + q * 4]);
    }
    float pa[8], ad[8], aa[8], a2r[8];
#pragma unroll
    for (int q = 0; q < 8; q += 4) {
        float4 t = *reinterpret_cast<const float4*>(&P[(size_t)node * 256 + f0 + q]);
        pa[q] = t.x; pa[q + 1] = t.y; pa[q + 2] = t.z; pa[q + 3] = t.w;
        float4 t2 = *reinterpret_cast<const float4*>(&A1d[f0 + q]);
        ad[q] = t2.x; ad[q + 1] = t2.y; ad[q + 2] = t2.z; ad[q + 3] = t2.w;
        float4 t3 = *reinterpret_cast<const float4*>(&a1v[f0 + q]);
        aa[q] = t3.x; aa[q + 1] = t3.y; aa[q + 2] = t3.z; aa[q + 3] = t3.w;
        float4 t4 = *reinterpret_cast<const float4*>(&A2v[f0 + q]);
        a2r[q] = t4.x; a2r[q + 1] = t4.y; a2r[q + 2] = t4.z; a2r[q + 3] = t4.w;
    }
#pragma unroll
    for (int eq = 0; eq < 4; ++eq) {
        int j4[4] = {ji[eq].x, ji[eq].y, ji[eq].z, ji[eq].w};
        float d4[4] = {di[eq].x, di[eq].y, di[eq].z, di[eq].w};
        float4 va[4], vb[4];
#pragma unroll
        for (int e = 0; e < 4; ++e) {
            const float* vp = &P[(size_t)(bbase + j4[e]) * 256 + 128 + f0];
            va[e] = *reinterpret_cast<const float4*>(&vp[0]);
            vb[e] = *reinterpret_cast<const float4*>(&vp[4]);
        }
#pragma unroll
        for (int e = 0; e < 4; ++e) {
            float dd = d4[e];
            float v8[8] = {va[e].x, va[e].y, va[e].z, va[e].w,
                           vb[e].x, vb[e].y, vb[e].z, vb[e].w};
            float part = 0.f;
#pragma unroll
            for (int w = 0; w < 8; ++w) {
                float pre = pa[w] + v8[w] + fmaf(dd, ad[w], aa[w]);
                part = fmaf(silu_f(pre), a2r[w], part);
            }
            plds[eq * 4 + e][(g << 4) | fc] = part;
        }
    }
    __syncthreads();
    {
        int g2 = threadIdx.x >> 4, e2 = threadIdx.x & 15;
        float w = a2v[0];
#pragma unroll
        for (int f2 = 0; f2 < 16; ++f2) w += plds[e2][(g2 << 4) | f2];
        wlds[g2][e2] = w;
    }
    __syncthreads();
    if (threadIdx.x < 48) {
        int gg = threadIdx.x & 15, c = threadIdx.x >> 4;
        int noded = node0 + gg;
        float dc = 0.f;
#pragma unroll
        for (int e = 0; e < K_; ++e)
            dc = fmaf(wlds[gg][e], nvec[(size_t)(noded * K_ + e) * 3 + c], dc);
        dclds[gg][c] = dc;
    }
    __syncthreads();
    if (threadIdx.x < 48) {
        int gg = threadIdx.x & 15, c = threadIdx.x >> 4;
        int noded = node0 + gg;
        const float* cb = cell + batch * 9;
        float c00 = cb[0], c01 = cb[1], c02 = cb[2];
        float c10 = cb[3], c11 = cb[4], c12 = cb[5];
        float c20 = cb[6], c21 = cb[7], c22 = cb[8];
        float det = c00 * (c11 * c22 - c12 * c21) - c01 * (c10 * c22 - c12 * c20) +
                    c02 * (c10 * c21 - c11 * c20);
        float rdet = 1.0f / det;
        float i0c, i1c, i2c;
        if (c == 0) {
            i0c = (c11 * c22 - c12 * c21) * rdet;
            i1c = -(c10 * c22 - c12 * c20) * rdet;
            i2c = (c10 * c21 - c11 * c20) * rdet;
        } else if (c == 1) {
            i0c = -(c01 * c22 - c02 * c21) * rdet;
            i1c = (c00 * c22 - c02 * c20) * rdet;
            i2c = -(c00 * c21 - c01 * c20) * rdet;
        } else {
            i0c = (c01 * c12 - c02 * c11) * rdet;
            i1c = -(c00 * c12 - c02 * c10) * rdet;
            i2c = (c00 * c11 - c01 * c10) * rdet;
        }
        float df = dclds[gg][0] * i0c + dclds[gg][1] * i1c + dclds[gg][2] * i2c;
        out[(size_t)noded * 3 + c] = x[(size_t)noded * 3 + c] + df;
    }
}

extern "C" void kernel_launch(void* const* d_in, const int* in_sizes, int n_in,
                              void* d_out, int out_size, void* d_ws, size_t ws_size,
                              hipStream_t stream) {
    (void)in_sizes; (void)n_in; (void)out_size; (void)ws_size;
    const float* cell = (const float*)d_in[0];
    const float* x    = (const float*)d_in[1];
    const int*   z    = (const int*)d_in[2];
    const float* emb  = (const float*)d_in[4];
    const float* W1   = (const float*)d_in[5];
    const float* b1   = (const float*)d_in[6];
    const float* W2   = (const float*)d_in[7];
    const float* b2   = (const float*)d_in[8];
    const float* A1   = (const float*)d_in[9];
    const float* a1   = (const float*)d_in[10];
    const float* A2   = (const float*)d_in[11];
    const float* a2   = (const float*)d_in[12];
    float* out = (float*)d_out;

    char* ws = (char*)d_ws;
    size_t off = 0;
    auto alloc = [&](size_t bytes) {
        void* p = ws + off;
        off = (off + bytes + 255) & ~(size_t)255;
        return p;
    };
    int* idx    = (int*)alloc((size_t)B_ * N_ * K_ * 4);
    float* nd   = (float*)alloc((size_t)B_ * N_ * K_ * 4);
    float* nvec = (float*)alloc((size_t)B_ * N_ * K_ * 3 * 4);
    float* h0   = (float*)alloc((size_t)B_ * N_ * F_ * 4);
    float* uv0  = (float*)alloc((size_t)B_ * N_ * 256 * 4);
    float* uv1  = (float*)alloc((size_t)B_ * N_ * 256 * 4);
    unsigned short* hbf = (unsigned short*)alloc((size_t)B_ * N_ * F_ * 2);
    unsigned short* Wt1 = (unsigned short*)alloc((size_t)L_ * 256 * 128 * 2);
    unsigned short* Wt2 = (unsigned short*)alloc((size_t)L_ * 128 * 128 * 2);
    unsigned short* At1 = (unsigned short*)alloc((size_t)256 * 128 * 2);

    k_prep<<<2048, 256, 0, stream>>>(z, emb, W1, W2, A1, h0, hbf, Wt1, Wt2, At1);
    k_front<<<5120, 256, 0, stream>>>(x, cell, idx, nvec, nd, hbf, Wt1, uv0);

    for (int l = 0; l < L_; ++l) {
        const float* uin = (l & 1) ? uv1 : uv0;
        float* uout = (l & 1) ? uv0 : uv1;
        const unsigned short* W1next = (l < 3) ? (Wt1 + (size_t)(l + 1) * 256 * 128) : At1;
        k_layer8<<<2048, 256, 0, stream>>>(uin, idx, nd,
                                           W1 + (size_t)l * DIN_ * F_ + 256 * F_,
                                           b1 + l * F_, Wt2 + (size_t)l * 128 * 128,
                                           b2 + l * F_, h0, W1next, uout);
    }
    k_final<<<1024, 256, 0, stream>>>(uv0, idx, nd, nvec, A1 + 256 * F_, a1, A2, a2, x, cell,
                                      out);
}

// Round 13
// 268.130 us; speedup vs baseline: 1.0653x; 1.0653x over previous
//
#include <hip/hip_runtime.h>

#define B_ 16
#define N_ 1024
#define K_ 16
#define F_ 128
#define L_ 4
#define DIN_ 257

typedef __bf16 bf16x8 __attribute__((ext_vector_type(8)));
typedef float f32x4 __attribute__((ext_vector_type(4)));

__device__ __forceinline__ float silu_f(float x) {
    return x / (1.0f + __expf(-x));
}

__device__ __forceinline__ unsigned short f2bf_bits(float f) {
    unsigned u = __builtin_bit_cast(unsigned, f);
    return (unsigned short)((u + 0x7FFFu + ((u >> 16) & 1u)) >> 16);
}

// ---------------- prep: weight pack/convert + embed (fused) ----------------
__global__ __launch_bounds__(256) void k_prep(const int* __restrict__ z,
                                              const float* __restrict__ emb,
                                              const float* __restrict__ W1,
                                              const float* __restrict__ W2,
                                              const float* __restrict__ A1,
                                              float* __restrict__ h,
                                              unsigned short* __restrict__ hbf,
                                              unsigned short* __restrict__ Wt1,
                                              unsigned short* __restrict__ Wt2,
                                              unsigned short* __restrict__ At1) {
    int gid = blockIdx.x * 256 + threadIdx.x;
    int id = gid;
    if (id < L_ * 256 * 128) {
        int k = id & 127, n = (id >> 7) & 255, l = id >> 15;
        float v = (n < 128) ? W1[(size_t)l * DIN_ * F_ + (size_t)k * F_ + n]
                            : W1[(size_t)l * DIN_ * F_ + (size_t)(128 + k) * F_ + (n - 128)];
        Wt1[id] = f2bf_bits(v);
    } else {
        int id2 = id - L_ * 256 * 128;
        if (id2 < L_ * 128 * 128) {
            int k = id2 & 127, n = (id2 >> 7) & 127, l = id2 >> 14;
            Wt2[id2] = f2bf_bits(W2[(size_t)l * F_ * F_ + (size_t)k * F_ + n]);
        } else {
            int id3 = id2 - L_ * 128 * 128;
            if (id3 < 256 * 128) {
                int k = id3 & 127, n = id3 >> 7;
                float v = (n < 128) ? A1[(size_t)k * 128 + n]
                                    : A1[(size_t)(128 + k) * 128 + (n - 128)];
                At1[id3] = f2bf_bits(v);
            }
        }
    }
    {
        int t = gid;
        int node = t >> 5;
        int f4 = (t & 31) << 2;
        int zi = z[node];
        float4 v = *reinterpret_cast<const float4*>(&emb[zi * F_ + f4]);
        *reinterpret_cast<float4*>(&h[node * F_ + f4]) = v;
        ushort4 pk;
        pk.x = f2bf_bits(v.x); pk.y = f2bf_bits(v.y);
        pk.z = f2bf_bits(v.z); pk.w = f2bf_bits(v.w);
        *reinterpret_cast<ushort4*>(&hbf[node * F_ + f4]) = pk;
    }
}

// ---------------- front: G1-layer0 GEMM (blocks 0..1023) || KNN (1024..5119) ----------------
// GEMM blocks dispatched first so they finish inside KNN's ramp; branch is
// blockIdx-uniform (no sync hazard). GEMM branch uses per-ks loads (low VGPR)
// so the KNN branch's occupancy is untaxed. KNN body verbatim from r4/r8
// (bit-identical numerics); GEMM acc-chain order identical to k_wgemm.
__global__ __launch_bounds__(256) void k_front(const float* __restrict__ x,
                                               const float* __restrict__ cell,
                                               int* __restrict__ idx_o,
                                               float* __restrict__ vec_o,
                                               float* __restrict__ d_o,
                                               const unsigned short* __restrict__ hbf,
                                               const unsigned short* __restrict__ Wt1,
                                               float* __restrict__ uv0) {
    __shared__ float fr[N_ * 3];
    int gb = blockIdx.x;
    int wave = threadIdx.x >> 6;
    int lane = threadIdx.x & 63;

    if (gb < 1024) {
        // ---- G1 of layer 0: uv0 = hbf @ Wt1(l=0) ----
        int tile = gb * 4 + wave;
        int mt = tile >> 3, nt = tile & 7;
        int fr16 = lane & 15, ko = lane >> 4;
        const unsigned short* Ap = hbf + (size_t)(mt * 32 + fr16) * 128 + ko * 8;
        const unsigned short* Bp = Wt1 + (size_t)(nt * 32 + fr16) * 128 + ko * 8;
        f32x4 acc00 = {0.f, 0.f, 0.f, 0.f}, acc01 = acc00, acc10 = acc00, acc11 = acc00;
#pragma unroll
        for (int ks = 0; ks < 4; ++ks) {
            bf16x8 a0 = *reinterpret_cast<const bf16x8*>(Ap + ks * 32);
            bf16x8 a1 = *reinterpret_cast<const bf16x8*>(Ap + 16 * 128 + ks * 32);
            bf16x8 b0 = *reinterpret_cast<const bf16x8*>(Bp + ks * 32);
            bf16x8 b1 = *reinterpret_cast<const bf16x8*>(Bp + 16 * 128 + ks * 32);
            acc00 = __builtin_amdgcn_mfma_f32_16x16x32_bf16(a0, b0, acc00, 0, 0, 0);
            acc01 = __builtin_amdgcn_mfma_f32_16x16x32_bf16(a0, b1, acc01, 0, 0, 0);
            acc10 = __builtin_amdgcn_mfma_f32_16x16x32_bf16(a1, b0, acc10, 0, 0, 0);
            acc11 = __builtin_amdgcn_mfma_f32_16x16x32_bf16(a1, b1, acc11, 0, 0, 0);
        }
        int mrow = mt * 32 + ko * 4;
        int cbase = nt * 32 + fr16;
#define EPI_(FM, FN, ACC)                                                    \
    {                                                                        \
        int cc = cbase + FN * 16;                                            \
        _Pragma("unroll") for (int r = 0; r < 4; ++r) {                      \
            int row = mrow + FM * 16 + r;                                    \
            uv0[(size_t)row * 256 + cc] = ACC[r];                            \
        }                                                                    \
    }
        EPI_(0, 0, acc00) EPI_(0, 1, acc01) EPI_(1, 0, acc10) EPI_(1, 1, acc11)
#undef EPI_
        return;
    }

    // ---- periodic KNN: wave per row ----
    int kb = gb - 1024;
    int b = kb >> 8;
    int ib = (kb & 255) << 2;
    const float* xb = x + b * N_ * 3;
    for (int u = threadIdx.x; u < N_ * 3; u += 256) {
        float xv = xb[u];
        fr[u] = xv - floorf(xv);
    }
    __syncthreads();
    int i = ib + wave;

    const float* cb = cell + b * 9;
    float c00 = cb[0], c01 = cb[1], c02 = cb[2];
    float c10 = cb[3], c11 = cb[4], c12 = cb[5];
    float c20 = cb[6], c21 = cb[7], c22 = cb[8];
    float fi0 = fr[i * 3 + 0], fi1 = fr[i * 3 + 1], fi2 = fr[i * 3 + 2];

    unsigned long long k[16];
#pragma unroll
    for (int t = 0; t < 16; ++t) {
        int j = t * 64 + lane;
        float r0 = fr[j * 3 + 0] - fi0;
        float r1 = fr[j * 3 + 1] - fi1;
        float r2 = fr[j * 3 + 2] - fi2;
        float s0f = (r0 > 0.f) ? -1.f : 0.f;
        float s1f = (r1 > 0.f) ? -1.f : 0.f;
        float s2f = (r2 > 0.f) ? -1.f : 0.f;
        int sid_base = ((r0 > 0.f) ? 0 : 9) + ((r1 > 0.f) ? 0 : 3) + ((r2 > 0.f) ? 0 : 1);
        float rx0 = r0 + s0f, rx1 = r0 + (s0f + 1.0f);
        float ry0 = r1 + s1f, ry1 = r1 + (s1f + 1.0f);
        float rz0 = r2 + s2f, rz1 = r2 + (s2f + 1.0f);
        float best = 3e38f;
        int bsid = 0;
#pragma unroll
        for (int cbo = 0; cbo < 8; ++cbo) {  // bit2=i0, bit1=i1, bit0=i2 (ascending sid)
            float rs0 = (cbo & 4) ? rx1 : rx0;
            float rs1 = (cbo & 2) ? ry1 : ry0;
            float rs2 = (cbo & 1) ? rz1 : rz0;
            float cx = fmaf(rs2, c20, fmaf(rs1, c10, rs0 * c00));
            float cy = fmaf(rs2, c21, fmaf(rs1, c11, rs0 * c01));
            float cz = fmaf(rs2, c22, fmaf(rs1, c12, rs0 * c02));
            float d2 = fmaf(cz, cz, fmaf(cy, cy, cx * cx));
            int sid = sid_base + ((cbo >> 2) & 1) * 9 + ((cbo >> 1) & 1) * 3 + (cbo & 1);
            if (d2 < best) { best = d2; bsid = sid; }
        }
        if (j == i) best = 3e38f;
        unsigned db = __builtin_bit_cast(unsigned, best);
        k[t] = ((unsigned long long)db << 32) | (unsigned)((j << 5) | bsid);
    }

#define CE_(a, b)                                              \
    {                                                          \
        unsigned long long x_ = k[a], y_ = k[b];               \
        bool s_ = y_ < x_;                                     \
        k[a] = s_ ? y_ : x_;                                   \
        k[b] = s_ ? x_ : y_;                                   \
    }
    CE_(0,1) CE_(2,3) CE_(4,5) CE_(6,7) CE_(8,9) CE_(10,11) CE_(12,13) CE_(14,15)
    CE_(0,2) CE_(1,3) CE_(4,6) CE_(5,7) CE_(8,10) CE_(9,11) CE_(12,14) CE_(13,15)
    CE_(1,2) CE_(5,6) CE_(9,10) CE_(13,14)
    CE_(0,4) CE_(1,5) CE_(2,6) CE_(3,7) CE_(8,12) CE_(9,13) CE_(10,14) CE_(11,15)
    CE_(2,4) CE_(3,5) CE_(10,12) CE_(11,13)
    CE_(1,2) CE_(3,4) CE_(5,6) CE_(9,10) CE_(11,12) CE_(13,14)
    CE_(0,8) CE_(1,9) CE_(2,10) CE_(3,11) CE_(4,12) CE_(5,13) CE_(6,14) CE_(7,15)
    CE_(4,8) CE_(5,9) CE_(6,10) CE_(7,11)
    CE_(2,4) CE_(3,5) CE_(6,8) CE_(7,9) CE_(10,12) CE_(11,13)
    CE_(1,2) CE_(3,4) CE_(5,6) CE_(7,8) CE_(9,10) CE_(11,12) CE_(13,14)
#undef CE_

    unsigned long long sel = 0;
    for (int r = 0; r < 16; ++r) {
        unsigned long long m = k[0];
#pragma unroll
        for (int off = 32; off >= 1; off >>= 1) {
            unsigned long long o = __shfl_xor(m, off);
            if (o < m) m = o;
        }
        if (k[0] == m) {
#pragma unroll
            for (int t = 0; t < 15; ++t) k[t] = k[t + 1];
            k[15] = ~0ull;
        }
        if (lane == r) sel = m;
    }

    if (lane < 16) {
        unsigned pk = (unsigned)sel;
        int j = pk >> 5, sid = pk & 31;
        int s0 = sid / 9 - 1, s1 = (sid / 3) % 3 - 1, s2 = sid % 3 - 1;
        float rs0 = (fr[j * 3 + 0] - fi0) + (float)s0;
        float rs1 = (fr[j * 3 + 1] - fi1) + (float)s1;
        float rs2 = (fr[j * 3 + 2] - fi2) + (float)s2;
        float vx = fmaf(rs2, c20, fmaf(rs1, c10, rs0 * c00));
        float vy = fmaf(rs2, c21, fmaf(rs1, c11, rs0 * c01));
        float vz = fmaf(rs2, c22, fmaf(rs1, c12, rs0 * c02));
        float d2 = fmaf(vz, vz, fmaf(vy, vy, vx * vx));
        float dd = sqrtf(fmaxf(d2, 1e-12f));
        int node = b * N_ + i;
        int eo = node * K_ + lane;
        idx_o[eo] = j;
        d_o[eo] = dd;
        vec_o[eo * 3 + 0] = vx;
        vec_o[eo * 3 + 1] = vy;
        vec_o[eo * 3 + 2] = vz;
    }
}

// ---------------- fused layer, 16 nodes/block (r8/r11 validated, verbatim) ----------------
__global__ __launch_bounds__(256) void k_layer16(const float* __restrict__ UVin,
                                                 const int* __restrict__ idx,
                                                 const float* __restrict__ nd,
                                                 const float* __restrict__ w1d,
                                                 const float* __restrict__ b1l,
                                                 const unsigned short* __restrict__ W2t,
                                                 const float* __restrict__ b2l,
                                                 float* __restrict__ h,
                                                 const unsigned short* __restrict__ W1n,
                                                 float* __restrict__ UVout) {
    __shared__ unsigned short svl[16][136];
    __shared__ unsigned short hbl[16][136];
    int tid = threadIdx.x;
    int gb = blockIdx.x;
    int batch = (gb & 7) + 8 * (gb >> 9);
    int ib = (gb >> 3) & 63;
    int node0 = batch * N_ + ib * 16;
    int bbase = batch * N_;
    int wave = tid >> 6, lane = tid & 63;
    int fr16 = lane & 15, ko = lane >> 4;

    {
        int gn = tid >> 4, fc = tid & 15, f0 = fc << 3;
        int node = node0 + gn;
        int4 ji[4];
        float4 di[4];
#pragma unroll
        for (int q = 0; q < 4; ++q) {
            ji[q] = *reinterpret_cast<const int4*>(&idx[node * K_ + q * 4]);
            di[q] = *reinterpret_cast<const float4*>(&nd[node * K_ + q * 4]);
        }
        float u[8], wd[8], bb[8], acc[8];
#pragma unroll
        for (int q = 0; q < 8; q += 4) {
            float4 t = *reinterpret_cast<const float4*>(&UVin[(size_t)node * 256 + f0 + q]);
            u[q] = t.x; u[q + 1] = t.y; u[q + 2] = t.z; u[q + 3] = t.w;
            float4 t2 = *reinterpret_cast<const float4*>(&w1d[f0 + q]);
            wd[q] = t2.x; wd[q + 1] = t2.y; wd[q + 2] = t2.z; wd[q + 3] = t2.w;
            float4 t3 = *reinterpret_cast<const float4*>(&b1l[f0 + q]);
            bb[q] = t3.x; bb[q + 1] = t3.y; bb[q + 2] = t3.z; bb[q + 3] = t3.w;
        }
#pragma unroll
        for (int q = 0; q < 8; ++q) acc[q] = 0.f;
#pragma unroll
        for (int eq = 0; eq < 4; ++eq) {
            int j4[4] = {ji[eq].x, ji[eq].y, ji[eq].z, ji[eq].w};
            float d4[4] = {di[eq].x, di[eq].y, di[eq].z, di[eq].w};
            float4 va[4], vb[4];
#pragma unroll
            for (int e = 0; e < 4; ++e) {
                const float* vp = &UVin[(size_t)(bbase + j4[e]) * 256 + 128 + f0];
                va[e] = *reinterpret_cast<const float4*>(&vp[0]);
                vb[e] = *reinterpret_cast<const float4*>(&vp[4]);
            }
#pragma unroll
            for (int e = 0; e < 4; ++e) {
                float dd = d4[e];
                float v8[8] = {va[e].x, va[e].y, va[e].z, va[e].w,
                               vb[e].x, vb[e].y, vb[e].z, vb[e].w};
#pragma unroll
                for (int w = 0; w < 8; ++w) {
                    float pre = u[w] + v8[w] + fmaf(dd, wd[w], bb[w]);
                    acc[w] += silu_f(pre);
                }
            }
        }
        const float inv_k = 1.0f / (float)K_;
        unsigned ow[4];
#pragma unroll
        for (int q = 0; q < 4; ++q)
            ow[q] = (unsigned)f2bf_bits(acc[2 * q] * inv_k) |
                    ((unsigned)f2bf_bits(acc[2 * q + 1] * inv_k) << 16);
        *reinterpret_cast<int4*>(&svl[gn][f0]) = make_int4(ow[0], ow[1], ow[2], ow[3]);
    }
    __syncthreads();

    {
        const unsigned short* Bp = W2t + (size_t)(wave * 32 + fr16) * 128 + ko * 8;
        bf16x8 a0[4], b0[4], b1f[4];
#pragma unroll
        for (int ks = 0; ks < 4; ++ks) {
            a0[ks] = *reinterpret_cast<const bf16x8*>(&svl[fr16][ks * 32 + ko * 8]);
            b0[ks] = *reinterpret_cast<const bf16x8*>(Bp + ks * 32);
            b1f[ks] = *reinterpret_cast<const bf16x8*>(Bp + 16 * 128 + ks * 32);
        }
        f32x4 acc00 = {0.f, 0.f, 0.f, 0.f}, acc01 = acc00;
#pragma unroll
        for (int ks = 0; ks < 4; ++ks) {
            acc00 = __builtin_amdgcn_mfma_f32_16x16x32_bf16(a0[ks], b0[ks], acc00, 0, 0, 0);
            acc01 = __builtin_amdgcn_mfma_f32_16x16x32_bf16(a0[ks], b1f[ks], acc01, 0, 0, 0);
        }
        int cb0 = wave * 32 + fr16;
#define EPI2_(FN, ACC)                                                         \
    {                                                                          \
        int col = cb0 + FN * 16;                                               \
        float bv = b2l[col];                                                   \
        _Pragma("unroll") for (int r = 0; r < 4; ++r) {                        \
            int row = ko * 4 + r;                                              \
            int grow = node0 + row;                                            \
            float val = ACC[r] + bv + h[(size_t)grow * 128 + col];             \
            h[(size_t)grow * 128 + col] = val;                                 \
            hbl[row][col] = f2bf_bits(val);                                    \
        }                                                                      \
    }
        EPI2_(0, acc00) EPI2_(1, acc01)
#undef EPI2_
    }
    __syncthreads();

#pragma unroll
    for (int half = 0; half < 2; ++half) {
        int nt2 = wave + half * 4;
        const unsigned short* Bp = W1n + (size_t)(nt2 * 32 + fr16) * 128 + ko * 8;
        bf16x8 a0[4], b0[4], b1f[4];
#pragma unroll
        for (int ks = 0; ks < 4; ++ks) {
            a0[ks] = *reinterpret_cast<const bf16x8*>(&hbl[fr16][ks * 32 + ko * 8]);
            b0[ks] = *reinterpret_cast<const bf16x8*>(Bp + ks * 32);
            b1f[ks] = *reinterpret_cast<const bf16x8*>(Bp + 16 * 128 + ks * 32);
        }
        f32x4 acc00 = {0.f, 0.f, 0.f, 0.f}, acc01 = acc00;
#pragma unroll
        for (int ks = 0; ks < 4; ++ks) {
            acc00 = __builtin_amdgcn_mfma_f32_16x16x32_bf16(a0[ks], b0[ks], acc00, 0, 0, 0);
            acc01 = __builtin_amdgcn_mfma_f32_16x16x32_bf16(a0[ks], b1f[ks], acc01, 0, 0, 0);
        }
        int cb0 = nt2 * 32 + fr16;
#define EPI1_(FN, ACC)                                                         \
    {                                                                          \
        int col = cb0 + FN * 16;                                               \
        _Pragma("unroll") for (int r = 0; r < 4; ++r) {                        \
            int row = ko * 4 + r;                                              \
            UVout[(size_t)(node0 + row) * 256 + col] = ACC[r];                 \
        }                                                                      \
    }
        EPI1_(0, acc00) EPI1_(1, acc01)
#undef EPI1_
    }
}

// ---------------- final head (r8/r11 validated, verbatim) ----------------
__global__ __launch_bounds__(256) void k_final(const float* __restrict__ P,
                                               const int* __restrict__ idx,
                                               const float* __restrict__ nd,
                                               const float* __restrict__ nvec,
                                               const float* __restrict__ A1d,
                                               const float* __restrict__ a1v,
                                               const float* __restrict__ A2v,
                                               const float* __restrict__ a2v,
                                               const float* __restrict__ x,
                                               const float* __restrict__ cell,
                                               float* __restrict__ out) {
    __shared__ float plds[16][256];
    __shared__ float wlds[16][17];
    __shared__ float dclds[16][3];
    int gb = blockIdx.x;
    int batch = (gb & 7) + 8 * (gb >> 9);
    int ib = (gb >> 3) & 63;
    int node0 = batch * N_ + ib * 16;
    int bbase = batch * N_;
    int g = threadIdx.x >> 4, fc = threadIdx.x & 15;
    int node = node0 + g;
    int f0 = fc * 8;
    int4 ji[4];
    float4 di[4];
#pragma unroll
    for (int q = 0; q < 4; ++q) {
        ji[q] = *reinterpret_cast<const int4*>(&idx[node * K_ + q * 4]);
        di[q] = *reinterpret_cast<const float4*>(&nd[node * K_ + q * 4]);
    }
    float pa[8], ad[8], aa[8], a2r[8];
#pragma unroll
    for (int q = 0; q < 8; q += 4) {
        float4 t = *reinterpret_cast<const float4*>(&P[(size_t)node * 256 + f0 + q]);
        pa[q] = t.x; pa[q + 1] = t.y; pa[q + 2] = t.z; pa[q + 3] = t.w;
        float4 t2 = *reinterpret_cast<const float4*>(&A1d[f0 + q]);
        ad[q] = t2.x; ad[q + 1] = t2.y; ad[q + 2] = t2.z; ad[q + 3] = t2.w;
        float4 t3 = *reinterpret_cast<const float4*>(&a1v[f0 + q]);
        aa[q] = t3.x; aa[q + 1] = t3.y; aa[q + 2] = t3.z; aa[q + 3] = t3.w;
        float4 t4 = *reinterpret_cast<const float4*>(&A2v[f0 + q]);
        a2r[q] = t4.x; a2r[q + 1] = t4.y; a2r[q + 2] = t4.z; a2r[q + 3] = t4.w;
    }
#pragma unroll
    for (int eq = 0; eq < 4; ++eq) {
        int j4[4] = {ji[eq].x, ji[eq].y, ji[eq].z, ji[eq].w};
        float d4[4] = {di[eq].x, di[eq].y, di[eq].z, di[eq].w};
        float4 va[4], vb[4];
#pragma unroll
        for (int e = 0; e < 4; ++e) {
            const float* vp = &P[(size_t)(bbase + j4[e]) * 256 + 128 + f0];
            va[e] = *reinterpret_cast<const float4*>(&vp[0]);
            vb[e] = *reinterpret_cast<const float4*>(&vp[4]);
        }
#pragma unroll
        for (int e = 0; e < 4; ++e) {
            float dd = d4[e];
            float v8[8] = {va[e].x, va[e].y, va[e].z, va[e].w,
                           vb[e].x, vb[e].y, vb[e].z, vb[e].w};
            float part = 0.f;
#pragma unroll
            for (int w = 0; w < 8; ++w) {
                float pre = pa[w] + v8[w] + fmaf(dd, ad[w], aa[w]);
                part = fmaf(silu_f(pre), a2r[w], part);
            }
            plds[eq * 4 + e][(g << 4) | fc] = part;
        }
    }
    __syncthreads();
    {
        int g2 = threadIdx.x >> 4, e2 = threadIdx.x & 15;
        float w = a2v[0];
#pragma unroll
        for (int f2 = 0; f2 < 16; ++f2) w += plds[e2][(g2 << 4) | f2];
        wlds[g2][e2] = w;
    }
    __syncthreads();
    if (threadIdx.x < 48) {
        int gg = threadIdx.x & 15, c = threadIdx.x >> 4;
        int noded = node0 + gg;
        float dc = 0.f;
#pragma unroll
        for (int e = 0; e < K_; ++e)
            dc = fmaf(wlds[gg][e], nvec[(size_t)(noded * K_ + e) * 3 + c], dc);
        dclds[gg][c] = dc;
    }
    __syncthreads();
    if (threadIdx.x < 48) {
        int gg = threadIdx.x & 15, c = threadIdx.x >> 4;
        int noded = node0 + gg;
        const float* cb = cell + batch * 9;
        float c00 = cb[0], c01 = cb[1], c02 = cb[2];
        float c10 = cb[3], c11 = cb[4], c12 = cb[5];
        float c20 = cb[6], c21 = cb[7], c22 = cb[8];
        float det = c00 * (c11 * c22 - c12 * c21) - c01 * (c10 * c22 - c12 * c20) +
                    c02 * (c10 * c21 - c11 * c20);
        float rdet = 1.0f / det;
        float i0c, i1c, i2c;
        if (c == 0) {
            i0c = (c11 * c22 - c12 * c21) * rdet;
            i1c = -(c10 * c22 - c12 * c20) * rdet;
            i2c = (c10 * c21 - c11 * c20) * rdet;
        } else if (c == 1) {
            i0c = -(c01 * c22 - c02 * c21) * rdet;
            i1c = (c00 * c22 - c02 * c20) * rdet;
            i2c = -(c00 * c21 - c01 * c20) * rdet;
        } else {
            i0c = (c01 * c12 - c02 * c11) * rdet;
            i1c = -(c00 * c12 - c02 * c10) * rdet;
            i2c = (c00 * c11 - c01 * c10) * rdet;
        }
        float df = dclds[gg][0] * i0c + dclds[gg][1] * i1c + dclds[gg][2] * i2c;
        out[(size_t)noded * 3 + c] = x[(size_t)noded * 3 + c] + df;
    }
}

extern "C" void kernel_launch(void* const* d_in, const int* in_sizes, int n_in,
                              void* d_out, int out_size, void* d_ws, size_t ws_size,
                              hipStream_t stream) {
    (void)in_sizes; (void)n_in; (void)out_size; (void)ws_size;
    const float* cell = (const float*)d_in[0];
    const float* x    = (const float*)d_in[1];
    const int*   z    = (const int*)d_in[2];
    const float* emb  = (const float*)d_in[4];
    const float* W1   = (const float*)d_in[5];
    const float* b1   = (const float*)d_in[6];
    const float* W2   = (const float*)d_in[7];
    const float* b2   = (const float*)d_in[8];
    const float* A1   = (const float*)d_in[9];
    const float* a1   = (const float*)d_in[10];
    const float* A2   = (const float*)d_in[11];
    const float* a2   = (const float*)d_in[12];
    float* out = (float*)d_out;

    char* ws = (char*)d_ws;
    size_t off = 0;
    auto alloc = [&](size_t bytes) {
        void* p = ws + off;
        off = (off + bytes + 255) & ~(size_t)255;
        return p;
    };
    int* idx    = (int*)alloc((size_t)B_ * N_ * K_ * 4);
    float* nd   = (float*)alloc((size_t)B_ * N_ * K_ * 4);
    float* nvec = (float*)alloc((size_t)B_ * N_ * K_ * 3 * 4);
    float* h0   = (float*)alloc((size_t)B_ * N_ * F_ * 4);
    float* uv0  = (float*)alloc((size_t)B_ * N_ * 256 * 4);
    float* uv1  = (float*)alloc((size_t)B_ * N_ * 256 * 4);
    unsigned short* hbf = (unsigned short*)alloc((size_t)B_ * N_ * F_ * 2);
    unsigned short* Wt1 = (unsigned short*)alloc((size_t)L_ * 256 * 128 * 2);
    unsigned short* Wt2 = (unsigned short*)alloc((size_t)L_ * 128 * 128 * 2);
    unsigned short* At1 = (unsigned short*)alloc((size_t)256 * 128 * 2);

    k_prep<<<2048, 256, 0, stream>>>(z, emb, W1, W2, A1, h0, hbf, Wt1, Wt2, At1);
    k_front<<<5120, 256, 0, stream>>>(x, cell, idx, nvec, nd, hbf, Wt1, uv0);

    for (int l = 0; l < L_; ++l) {
        const float* uin = (l & 1) ? uv1 : uv0;
        float* uout = (l & 1) ? uv0 : uv1;
        const unsigned short* W1next = (l < 3) ? (Wt1 + (size_t)(l + 1) * 256 * 128) : At1;
        k_layer16<<<1024, 256, 0, stream>>>(uin, idx, nd,
                                            W1 + (size_t)l * DIN_ * F_ + 256 * F_,
                                            b1 + l * F_, Wt2 + (size_t)l * 128 * 128,
                                            b2 + l * F_, h0, W1next, uout);
    }
    k_final<<<1024, 256, 0, stream>>>(uv0, idx, nd, nvec, A1 + 256 * F_, a1, A2, a2, x, cell,
                                      out);
}

// Round 14
// 267.988 us; speedup vs baseline: 1.0659x; 1.0005x over previous
//
#include <hip/hip_runtime.h>

#define B_ 16
#define N_ 1024
#define K_ 16
#define F_ 128
#define L_ 4
#define DIN_ 257

typedef __bf16 bf16x8 __attribute__((ext_vector_type(8)));
typedef float f32x4 __attribute__((ext_vector_type(4)));

__device__ __forceinline__ float silu_f(float x) {
    return x / (1.0f + __expf(-x));
}

__device__ __forceinline__ unsigned short f2bf_bits(float f) {
    unsigned u = __builtin_bit_cast(unsigned, f);
    return (unsigned short)((u + 0x7FFFu + ((u >> 16) & 1u)) >> 16);
}

// ---------------- prep: weight pack/convert + embed (fused) ----------------
__global__ __launch_bounds__(256) void k_prep(const int* __restrict__ z,
                                              const float* __restrict__ emb,
                                              const float* __restrict__ W1,
                                              const float* __restrict__ W2,
                                              const float* __restrict__ A1,
                                              float* __restrict__ h,
                                              unsigned short* __restrict__ hbf,
                                              unsigned short* __restrict__ Wt1,
                                              unsigned short* __restrict__ Wt2,
                                              unsigned short* __restrict__ At1) {
    int gid = blockIdx.x * 256 + threadIdx.x;
    int id = gid;
    if (id < L_ * 256 * 128) {
        int k = id & 127, n = (id >> 7) & 255, l = id >> 15;
        float v = (n < 128) ? W1[(size_t)l * DIN_ * F_ + (size_t)k * F_ + n]
                            : W1[(size_t)l * DIN_ * F_ + (size_t)(128 + k) * F_ + (n - 128)];
        Wt1[id] = f2bf_bits(v);
    } else {
        int id2 = id - L_ * 256 * 128;
        if (id2 < L_ * 128 * 128) {
            int k = id2 & 127, n = (id2 >> 7) & 127, l = id2 >> 14;
            Wt2[id2] = f2bf_bits(W2[(size_t)l * F_ * F_ + (size_t)k * F_ + n]);
        } else {
            int id3 = id2 - L_ * 128 * 128;
            if (id3 < 256 * 128) {
                int k = id3 & 127, n = id3 >> 7;
                float v = (n < 128) ? A1[(size_t)k * 128 + n]
                                    : A1[(size_t)(128 + k) * 128 + (n - 128)];
                At1[id3] = f2bf_bits(v);
            }
        }
    }
    {
        int t = gid;
        int node = t >> 5;
        int f4 = (t & 31) << 2;
        int zi = z[node];
        float4 v = *reinterpret_cast<const float4*>(&emb[zi * F_ + f4]);
        *reinterpret_cast<float4*>(&h[node * F_ + f4]) = v;
        ushort4 pk;
        pk.x = f2bf_bits(v.x); pk.y = f2bf_bits(v.y);
        pk.z = f2bf_bits(v.z); pk.w = f2bf_bits(v.w);
        *reinterpret_cast<ushort4*>(&hbf[node * F_ + f4]) = pk;
    }
}

// ---------------- front: G1-layer0 GEMM (blocks 0..1023) || KNN (1024..5119) ----------------
// GEMM blocks dispatched first so they finish inside KNN's ramp; branch is
// blockIdx-uniform (no sync hazard). GEMM branch uses per-ks loads (low VGPR)
// so the KNN branch's occupancy is untaxed. KNN body verbatim from r4/r8
// (bit-identical numerics); GEMM acc-chain order identical to k_wgemm.
__global__ __launch_bounds__(256) void k_front(const float* __restrict__ x,
                                               const float* __restrict__ cell,
                                               int* __restrict__ idx_o,
                                               float* __restrict__ vec_o,
                                               float* __restrict__ d_o,
                                               const unsigned short* __restrict__ hbf,
                                               const unsigned short* __restrict__ Wt1,
                                               float* __restrict__ uv0) {
    __shared__ float fr[N_ * 3];
    int gb = blockIdx.x;
    int wave = threadIdx.x >> 6;
    int lane = threadIdx.x & 63;

    if (gb < 1024) {
        // ---- G1 of layer 0: uv0 = hbf @ Wt1(l=0) ----
        int tile = gb * 4 + wave;
        int mt = tile >> 3, nt = tile & 7;
        int fr16 = lane & 15, ko = lane >> 4;
        const unsigned short* Ap = hbf + (size_t)(mt * 32 + fr16) * 128 + ko * 8;
        const unsigned short* Bp = Wt1 + (size_t)(nt * 32 + fr16) * 128 + ko * 8;
        f32x4 acc00 = {0.f, 0.f, 0.f, 0.f}, acc01 = acc00, acc10 = acc00, acc11 = acc00;
#pragma unroll
        for (int ks = 0; ks < 4; ++ks) {
            bf16x8 a0 = *reinterpret_cast<const bf16x8*>(Ap + ks * 32);
            bf16x8 a1 = *reinterpret_cast<const bf16x8*>(Ap + 16 * 128 + ks * 32);
            bf16x8 b0 = *reinterpret_cast<const bf16x8*>(Bp + ks * 32);
            bf16x8 b1 = *reinterpret_cast<const bf16x8*>(Bp + 16 * 128 + ks * 32);
            acc00 = __builtin_amdgcn_mfma_f32_16x16x32_bf16(a0, b0, acc00, 0, 0, 0);
            acc01 = __builtin_amdgcn_mfma_f32_16x16x32_bf16(a0, b1, acc01, 0, 0, 0);
            acc10 = __builtin_amdgcn_mfma_f32_16x16x32_bf16(a1, b0, acc10, 0, 0, 0);
            acc11 = __builtin_amdgcn_mfma_f32_16x16x32_bf16(a1, b1, acc11, 0, 0, 0);
        }
        int mrow = mt * 32 + ko * 4;
        int cbase = nt * 32 + fr16;
#define EPI_(FM, FN, ACC)                                                    \
    {                                                                        \
        int cc = cbase + FN * 16;                                            \
        _Pragma("unroll") for (int r = 0; r < 4; ++r) {                      \
            int row = mrow + FM * 16 + r;                                    \
            uv0[(size_t)row * 256 + cc] = ACC[r];                            \
        }                                                                    \
    }
        EPI_(0, 0, acc00) EPI_(0, 1, acc01) EPI_(1, 0, acc10) EPI_(1, 1, acc11)
#undef EPI_
        return;
    }

    // ---- periodic KNN: wave per row ----
    int kb = gb - 1024;
    int b = kb >> 8;
    int ib = (kb & 255) << 2;
    const float* xb = x + b * N_ * 3;
    for (int u = threadIdx.x; u < N_ * 3; u += 256) {
        float xv = xb[u];
        fr[u] = xv - floorf(xv);
    }
    __syncthreads();
    int i = ib + wave;

    const float* cb = cell + b * 9;
    float c00 = cb[0], c01 = cb[1], c02 = cb[2];
    float c10 = cb[3], c11 = cb[4], c12 = cb[5];
    float c20 = cb[6], c21 = cb[7], c22 = cb[8];
    float fi0 = fr[i * 3 + 0], fi1 = fr[i * 3 + 1], fi2 = fr[i * 3 + 2];

    unsigned long long k[16];
#pragma unroll
    for (int t = 0; t < 16; ++t) {
        int j = t * 64 + lane;
        float r0 = fr[j * 3 + 0] - fi0;
        float r1 = fr[j * 3 + 1] - fi1;
        float r2 = fr[j * 3 + 2] - fi2;
        float s0f = (r0 > 0.f) ? -1.f : 0.f;
        float s1f = (r1 > 0.f) ? -1.f : 0.f;
        float s2f = (r2 > 0.f) ? -1.f : 0.f;
        int sid_base = ((r0 > 0.f) ? 0 : 9) + ((r1 > 0.f) ? 0 : 3) + ((r2 > 0.f) ? 0 : 1);
        float rx0 = r0 + s0f, rx1 = r0 + (s0f + 1.0f);
        float ry0 = r1 + s1f, ry1 = r1 + (s1f + 1.0f);
        float rz0 = r2 + s2f, rz1 = r2 + (s2f + 1.0f);
        float best = 3e38f;
        int bsid = 0;
#pragma unroll
        for (int cbo = 0; cbo < 8; ++cbo) {  // bit2=i0, bit1=i1, bit0=i2 (ascending sid)
            float rs0 = (cbo & 4) ? rx1 : rx0;
            float rs1 = (cbo & 2) ? ry1 : ry0;
            float rs2 = (cbo & 1) ? rz1 : rz0;
            float cx = fmaf(rs2, c20, fmaf(rs1, c10, rs0 * c00));
            float cy = fmaf(rs2, c21, fmaf(rs1, c11, rs0 * c01));
            float cz = fmaf(rs2, c22, fmaf(rs1, c12, rs0 * c02));
            float d2 = fmaf(cz, cz, fmaf(cy, cy, cx * cx));
            int sid = sid_base + ((cbo >> 2) & 1) * 9 + ((cbo >> 1) & 1) * 3 + (cbo & 1);
            if (d2 < best) { best = d2; bsid = sid; }
        }
        if (j == i) best = 3e38f;
        unsigned db = __builtin_bit_cast(unsigned, best);
        k[t] = ((unsigned long long)db << 32) | (unsigned)((j << 5) | bsid);
    }

#define CE_(a, b)                                              \
    {                                                          \
        unsigned long long x_ = k[a], y_ = k[b];               \
        bool s_ = y_ < x_;                                     \
        k[a] = s_ ? y_ : x_;                                   \
        k[b] = s_ ? x_ : y_;                                   \
    }
    CE_(0,1) CE_(2,3) CE_(4,5) CE_(6,7) CE_(8,9) CE_(10,11) CE_(12,13) CE_(14,15)
    CE_(0,2) CE_(1,3) CE_(4,6) CE_(5,7) CE_(8,10) CE_(9,11) CE_(12,14) CE_(13,15)
    CE_(1,2) CE_(5,6) CE_(9,10) CE_(13,14)
    CE_(0,4) CE_(1,5) CE_(2,6) CE_(3,7) CE_(8,12) CE_(9,13) CE_(10,14) CE_(11,15)
    CE_(2,4) CE_(3,5) CE_(10,12) CE_(11,13)
    CE_(1,2) CE_(3,4) CE_(5,6) CE_(9,10) CE_(11,12) CE_(13,14)
    CE_(0,8) CE_(1,9) CE_(2,10) CE_(3,11) CE_(4,12) CE_(5,13) CE_(6,14) CE_(7,15)
    CE_(4,8) CE_(5,9) CE_(6,10) CE_(7,11)
    CE_(2,4) CE_(3,5) CE_(6,8) CE_(7,9) CE_(10,12) CE_(11,13)
    CE_(1,2) CE_(3,4) CE_(5,6) CE_(7,8) CE_(9,10) CE_(11,12) CE_(13,14)
#undef CE_

    unsigned long long sel = 0;
    for (int r = 0; r < 16; ++r) {
        unsigned long long m = k[0];
#pragma unroll
        for (int off = 32; off >= 1; off >>= 1) {
            unsigned long long o = __shfl_xor(m, off);
            if (o < m) m = o;
        }
        if (k[0] == m) {
#pragma unroll
            for (int t = 0; t < 15; ++t) k[t] = k[t + 1];
            k[15] = ~0ull;
        }
        if (lane == r) sel = m;
    }

    if (lane < 16) {
        unsigned pk = (unsigned)sel;
        int j = pk >> 5, sid = pk & 31;
        int s0 = sid / 9 - 1, s1 = (sid / 3) % 3 - 1, s2 = sid % 3 - 1;
        float rs0 = (fr[j * 3 + 0] - fi0) + (float)s0;
        float rs1 = (fr[j * 3 + 1] - fi1) + (float)s1;
        float rs2 = (fr[j * 3 + 2] - fi2) + (float)s2;
        float vx = fmaf(rs2, c20, fmaf(rs1, c10, rs0 * c00));
        float vy = fmaf(rs2, c21, fmaf(rs1, c11, rs0 * c01));
        float vz = fmaf(rs2, c22, fmaf(rs1, c12, rs0 * c02));
        float d2 = fmaf(vz, vz, fmaf(vy, vy, vx * vx));
        float dd = sqrtf(fmaxf(d2, 1e-12f));
        int node = b * N_ + i;
        int eo = node * K_ + lane;
        idx_o[eo] = j;
        d_o[eo] = dd;
        vec_o[eo * 3 + 0] = vx;
        vec_o[eo * 3 + 1] = vy;
        vec_o[eo * 3 + 2] = vz;
    }
}

// ---------------- fused layer, 16 nodes/block (r8/r11 validated, verbatim) ----------------
__global__ __launch_bounds__(256) void k_layer16(const float* __restrict__ UVin,
                                                 const int* __restrict__ idx,
                                                 const float* __restrict__ nd,
                                                 const float* __restrict__ w1d,
                                                 const float* __restrict__ b1l,
                                                 const unsigned short* __restrict__ W2t,
                                                 const float* __restrict__ b2l,
                                                 float* __restrict__ h,
                                                 const unsigned short* __restrict__ W1n,
                                                 float* __restrict__ UVout) {
    __shared__ unsigned short svl[16][136];
    __shared__ unsigned short hbl[16][136];
    int tid = threadIdx.x;
    int gb = blockIdx.x;
    int batch = (gb & 7) + 8 * (gb >> 9);
    int ib = (gb >> 3) & 63;
    int node0 = batch * N_ + ib * 16;
    int bbase = batch * N_;
    int wave = tid >> 6, lane = tid & 63;
    int fr16 = lane & 15, ko = lane >> 4;

    {
        int gn = tid >> 4, fc = tid & 15, f0 = fc << 3;
        int node = node0 + gn;
        int4 ji[4];
        float4 di[4];
#pragma unroll
        for (int q = 0; q < 4; ++q) {
            ji[q] = *reinterpret_cast<const int4*>(&idx[node * K_ + q * 4]);
            di[q] = *reinterpret_cast<const float4*>(&nd[node * K_ + q * 4]);
        }
        float u[8], wd[8], bb[8], acc[8];
#pragma unroll
        for (int q = 0; q < 8; q += 4) {
            float4 t = *reinterpret_cast<const float4*>(&UVin[(size_t)node * 256 + f0 + q]);
            u[q] = t.x; u[q + 1] = t.y; u[q + 2] = t.z; u[q + 3] = t.w;
            float4 t2 = *reinterpret_cast<const float4*>(&w1d[f0 + q]);
            wd[q] = t2.x; wd[q + 1] = t2.y; wd[q + 2] = t2.z; wd[q + 3] = t2.w;
            float4 t3 = *reinterpret_cast<const float4*>(&b1l[f0 + q]);
            bb[q] = t3.x; bb[q + 1] = t3.y; bb[q + 2] = t3.z; bb[q + 3] = t3.w;
        }
#pragma unroll
        for (int q = 0; q < 8; ++q) acc[q] = 0.f;
#pragma unroll
        for (int eq = 0; eq < 4; ++eq) {
            int j4[4] = {ji[eq].x, ji[eq].y, ji[eq].z, ji[eq].w};
            float d4[4] = {di[eq].x, di[eq].y, di[eq].z, di[eq].w};
            float4 va[4], vb[4];
#pragma unroll
            for (int e = 0; e < 4; ++e) {
                const float* vp = &UVin[(size_t)(bbase + j4[e]) * 256 + 128 + f0];
                va[e] = *reinterpret_cast<const float4*>(&vp[0]);
                vb[e] = *reinterpret_cast<const float4*>(&vp[4]);
            }
#pragma unroll
            for (int e = 0; e < 4; ++e) {
                float dd = d4[e];
                float v8[8] = {va[e].x, va[e].y, va[e].z, va[e].w,
                               vb[e].x, vb[e].y, vb[e].z, vb[e].w};
#pragma unroll
                for (int w = 0; w < 8; ++w) {
                    float pre = u[w] + v8[w] + fmaf(dd, wd[w], bb[w]);
                    acc[w] += silu_f(pre);
                }
            }
        }
        const float inv_k = 1.0f / (float)K_;
        unsigned ow[4];
#pragma unroll
        for (int q = 0; q < 4; ++q)
            ow[q] = (unsigned)f2bf_bits(acc[2 * q] * inv_k) |
                    ((unsigned)f2bf_bits(acc[2 * q + 1] * inv_k) << 16);
        *reinterpret_cast<int4*>(&svl[gn][f0]) = make_int4(ow[0], ow[1], ow[2], ow[3]);
    }
    __syncthreads();

    {
        const unsigned short* Bp = W2t + (size_t)(wave * 32 + fr16) * 128 + ko * 8;
        bf16x8 a0[4], b0[4], b1f[4];
#pragma unroll
        for (int ks = 0; ks < 4; ++ks) {
            a0[ks] = *reinterpret_cast<const bf16x8*>(&svl[fr16][ks * 32 + ko * 8]);
            b0[ks] = *reinterpret_cast<const bf16x8*>(Bp + ks * 32);
            b1f[ks] = *reinterpret_cast<const bf16x8*>(Bp + 16 * 128 + ks * 32);
        }
        f32x4 acc00 = {0.f, 0.f, 0.f, 0.f}, acc01 = acc00;
#pragma unroll
        for (int ks = 0; ks < 4; ++ks) {
            acc00 = __builtin_amdgcn_mfma_f32_16x16x32_bf16(a0[ks], b0[ks], acc00, 0, 0, 0);
            acc01 = __builtin_amdgcn_mfma_f32_16x16x32_bf16(a0[ks], b1f[ks], acc01, 0, 0, 0);
        }
        int cb0 = wave * 32 + fr16;
#define EPI2_(FN, ACC)                                                         \
    {                                                                          \
        int col = cb0 + FN * 16;                                               \
        float bv = b2l[col];                                                   \
        _Pragma("unroll") for (int r = 0; r < 4; ++r) {                        \
            int row = ko * 4 + r;                                              \
            int grow = node0 + row;                                            \
            float val = ACC[r] + bv + h[(size_t)grow * 128 + col];             \
            h[(size_t)grow * 128 + col] = val;                                 \
            hbl[row][col] = f2bf_bits(val);                                    \
        }                                                                      \
    }
        EPI2_(0, acc00) EPI2_(1, acc01)
#undef EPI2_
    }
    __syncthreads();

#pragma unroll
    for (int half = 0; half < 2; ++half) {
        int nt2 = wave + half * 4;
        const unsigned short* Bp = W1n + (size_t)(nt2 * 32 + fr16) * 128 + ko * 8;
        bf16x8 a0[4], b0[4], b1f[4];
#pragma unroll
        for (int ks = 0; ks < 4; ++ks) {
            a0[ks] = *reinterpret_cast<const bf16x8*>(&hbl[fr16][ks * 32 + ko * 8]);
            b0[ks] = *reinterpret_cast<const bf16x8*>(Bp + ks * 32);
            b1f[ks] = *reinterpret_cast<const bf16x8*>(Bp + 16 * 128 + ks * 32);
        }
        f32x4 acc00 = {0.f, 0.f, 0.f, 0.f}, acc01 = acc00;
#pragma unroll
        for (int ks = 0; ks < 4; ++ks) {
            acc00 = __builtin_amdgcn_mfma_f32_16x16x32_bf16(a0[ks], b0[ks], acc00, 0, 0, 0);
            acc01 = __builtin_amdgcn_mfma_f32_16x16x32_bf16(a0[ks], b1f[ks], acc01, 0, 0, 0);
        }
        int cb0 = nt2 * 32 + fr16;
#define EPI1_(FN, ACC)                                                         \
    {                                                                          \
        int col = cb0 + FN * 16;                                               \
        _Pragma("unroll") for (int r = 0; r < 4; ++r) {                        \
            int row = ko * 4 + r;                                              \
            UVout[(size_t)(node0 + row) * 256 + col] = ACC[r];                 \
        }                                                                      \
    }
        EPI1_(0, acc00) EPI1_(1, acc01)
#undef EPI1_
    }
}

// ---------------- final head (r8/r11 validated, verbatim) ----------------
__global__ __launch_bounds__(256) void k_final(const float* __restrict__ P,
                                               const int* __restrict__ idx,
                                               const float* __restrict__ nd,
                                               const float* __restrict__ nvec,
                                               const float* __restrict__ A1d,
                                               const float* __restrict__ a1v,
                                               const float* __restrict__ A2v,
                                               const float* __restrict__ a2v,
                                               const float* __restrict__ x,
                                               const float* __restrict__ cell,
                                               float* __restrict__ out) {
    __shared__ float plds[16][256];
    __shared__ float wlds[16][17];
    __shared__ float dclds[16][3];
    int gb = blockIdx.x;
    int batch = (gb & 7) + 8 * (gb >> 9);
    int ib = (gb >> 3) & 63;
    int node0 = batch * N_ + ib * 16;
    int bbase = batch * N_;
    int g = threadIdx.x >> 4, fc = threadIdx.x & 15;
    int node = node0 + g;
    int f0 = fc * 8;
    int4 ji[4];
    float4 di[4];
#pragma unroll
    for (int q = 0; q < 4; ++q) {
        ji[q] = *reinterpret_cast<const int4*>(&idx[node * K_ + q * 4]);
        di[q] = *reinterpret_cast<const float4*>(&nd[node * K_ + q * 4]);
    }
    float pa[8], ad[8], aa[8], a2r[8];
#pragma unroll
    for (int q = 0; q < 8; q += 4) {
        float4 t = *reinterpret_cast<const float4*>(&P[(size_t)node * 256 + f0 + q]);
        pa[q] = t.x; pa[q + 1] = t.y; pa[q + 2] = t.z; pa[q + 3] = t.w;
        float4 t2 = *reinterpret_cast<const float4*>(&A1d[f0 + q]);
        ad[q] = t2.x; ad[q + 1] = t2.y; ad[q + 2] = t2.z; ad[q + 3] = t2.w;
        float4 t3 = *reinterpret_cast<const float4*>(&a1v[f0 + q]);
        aa[q] = t3.x; aa[q + 1] = t3.y; aa[q + 2] = t3.z; aa[q + 3] = t3.w;
        float4 t4 = *reinterpret_cast<const float4*>(&A2v[f0 + q]);
        a2r[q] = t4.x; a2r[q + 1] = t4.y; a2r[q + 2] = t4.z; a2r[q + 3] = t4.w;
    }
#pragma unroll
    for (int eq = 0; eq < 4; ++eq) {
        int j4[4] = {ji[eq].x, ji[eq].y, ji[eq].z, ji[eq].w};
        float d4[4] = {di[eq].x, di[eq].y, di[eq].z, di[eq].w};
        float4 va[4], vb[4];
#pragma unroll
        for (int e = 0; e < 4; ++e) {
            const float* vp = &P[(size_t)(bbase + j4[e]) * 256 + 128 + f0];
            va[e] = *reinterpret_cast<const float4*>(&vp[0]);
            vb[e] = *reinterpret_cast<const float4*>(&vp[4]);
        }
#pragma unroll
        for (int e = 0; e < 4; ++e) {
            float dd = d4[e];
            float v8[8] = {va[e].x, va[e].y, va[e].z, va[e].w,
                           vb[e].x, vb[e].y, vb[e].z, vb[e].w};
            float part = 0.f;
#pragma unroll
            for (int w = 0; w < 8; ++w) {
                float pre = pa[w] + v8[w] + fmaf(dd, ad[w], aa[w]);
                part = fmaf(silu_f(pre), a2r[w], part);
            }
            plds[eq * 4 + e][(g << 4) | fc] = part;
        }
    }
    __syncthreads();
    {
        int g2 = threadIdx.x >> 4, e2 = threadIdx.x & 15;
        float w = a2v[0];
#pragma unroll
        for (int f2 = 0; f2 < 16; ++f2) w += plds[e2][(g2 << 4) | f2];
        wlds[g2][e2] = w;
    }
    __syncthreads();
    if (threadIdx.x < 48) {
        int gg = threadIdx.x & 15, c = threadIdx.x >> 4;
        int noded = node0 + gg;
        float dc = 0.f;
#pragma unroll
        for (int e = 0; e < K_; ++e)
            dc = fmaf(wlds[gg][e], nvec[(size_t)(noded * K_ + e) * 3 + c], dc);
        dclds[gg][c] = dc;
    }
    __syncthreads();
    if (threadIdx.x < 48) {
        int gg = threadIdx.x & 15, c = threadIdx.x >> 4;
        int noded = node0 + gg;
        const float* cb = cell + batch * 9;
        float c00 = cb[0], c01 = cb[1], c02 = cb[2];
        float c10 = cb[3], c11 = cb[4], c12 = cb[5];
        float c20 = cb[6], c21 = cb[7], c22 = cb[8];
        float det = c00 * (c11 * c22 - c12 * c21) - c01 * (c10 * c22 - c12 * c20) +
                    c02 * (c10 * c21 - c11 * c20);
        float rdet = 1.0f / det;
        float i0c, i1c, i2c;
        if (c == 0) {
            i0c = (c11 * c22 - c12 * c21) * rdet;
            i1c = -(c10 * c22 - c12 * c20) * rdet;
            i2c = (c10 * c21 - c11 * c20) * rdet;
        } else if (c == 1) {
            i0c = -(c01 * c22 - c02 * c21) * rdet;
            i1c = (c00 * c22 - c02 * c20) * rdet;
            i2c = -(c00 * c21 - c01 * c20) * rdet;
        } else {
            i0c = (c01 * c12 - c02 * c11) * rdet;
            i1c = -(c00 * c12 - c02 * c10) * rdet;
            i2c = (c00 * c11 - c01 * c10) * rdet;
        }
        float df = dclds[gg][0] * i0c + dclds[gg][1] * i1c + dclds[gg][2] * i2c;
        out[(size_t)noded * 3 + c] = x[(size_t)noded * 3 + c] + df;
    }
}

extern "C" void kernel_launch(void* const* d_in, const int* in_sizes, int n_in,
                              void* d_out, int out_size, void* d_ws, size_t ws_size,
                              hipStream_t stream) {
    (void)in_sizes; (void)n_in; (void)out_size; (void)ws_size;
    const float* cell = (const float*)d_in[0];
    const float* x    = (const float*)d_in[1];
    const int*   z    = (const int*)d_in[2];
    const float* emb  = (const float*)d_in[4];
    const float* W1   = (const float*)d_in[5];
    const float* b1   = (const float*)d_in[6];
    const float* W2   = (const float*)d_in[7];
    const float* b2   = (const float*)d_in[8];
    const float* A1   = (const float*)d_in[9];
    const float* a1   = (const float*)d_in[10];
    const float* A2   = (const float*)d_in[11];
    const float* a2   = (const float*)d_in[12];
    float* out = (float*)d_out;

    char* ws = (char*)d_ws;
    size_t off = 0;
    auto alloc = [&](size_t bytes) {
        void* p = ws + off;
        off = (off + bytes + 255) & ~(size_t)255;
        return p;
    };
    int* idx    = (int*)alloc((size_t)B_ * N_ * K_ * 4);
    float* nd   = (float*)alloc((size_t)B_ * N_ * K_ * 4);
    float* nvec = (float*)alloc((size_t)B_ * N_ * K_ * 3 * 4);
    float* h0   = (float*)alloc((size_t)B_ * N_ * F_ * 4);
    float* uv0  = (float*)alloc((size_t)B_ * N_ * 256 * 4);
    float* uv1  = (float*)alloc((size_t)B_ * N_ * 256 * 4);
    unsigned short* hbf = (unsigned short*)alloc((size_t)B_ * N_ * F_ * 2);
    unsigned short* Wt1 = (unsigned short*)alloc((size_t)L_ * 256 * 128 * 2);
    unsigned short* Wt2 = (unsigned short*)alloc((size_t)L_ * 128 * 128 * 2);
    unsigned short* At1 = (unsigned short*)alloc((size_t)256 * 128 * 2);

    k_prep<<<2048, 256, 0, stream>>>(z, emb, W1, W2, A1, h0, hbf, Wt1, Wt2, At1);
    k_front<<<5120, 256, 0, stream>>>(x, cell, idx, nvec, nd, hbf, Wt1, uv0);

    for (int l = 0; l < L_; ++l) {
        const float* uin = (l & 1) ? uv1 : uv0;
        float* uout = (l & 1) ? uv0 : uv1;
        const unsigned short* W1next = (l < 3) ? (Wt1 + (size_t)(l + 1) * 256 * 128) : At1;
        k_layer16<<<1024, 256, 0, stream>>>(uin, idx, nd,
                                            W1 + (size_t)l * DIN_ * F_ + 256 * F_,
                                            b1 + l * F_, Wt2 + (size_t)l * 128 * 128,
                                            b2 + l * F_, h0, W1next, uout);
    }
    k_final<<<1024, 256, 0, stream>>>(uv0, idx, nd, nvec, A1 + 256 * F_, a1, A2, a2, x, cell,
                                      out);
}